// Round 12
// baseline (250.265 us; speedup 1.0000x reference)
//
#include <hip/hip_runtime.h>

namespace {
constexpr int B_ = 8, H_ = 16, CI_ = 16, O_ = 16, P_ = 14;
constexpr int P2_ = P_ * P_;    // 196
constexpr int K2CI_ = 144;
constexpr int NV_ = 2304;       // z per patch, layout [k][o]
constexpr float EPS_ = 1e-9f;
constexpr float LOG2PI_ = 1.8378770664093453f;

using f2 = __attribute__((ext_vector_type(2))) float;

__device__ __forceinline__ float cnt1(int h) {
  int lo = (h - (P_ - 1)) > 0 ? (h - (P_ - 1)) : 0;
  int hi = h < 2 ? h : 2;
  return (float)(hi - lo + 1);
}

// Fused prologue: blocks [0,2048) transpose pose (4x4 per cell -> [q][p]);
// blocks [2048,2192) transpose w -> wt[k][o][r][q].
__global__ __launch_bounds__(256) void transpose_all(const float* __restrict__ pose,
                                                     float* __restrict__ pose_t,
                                                     const float* __restrict__ w,
                                                     float* __restrict__ wt) {
  if (blockIdx.x < 2048) {
    const int i = blockIdx.x * 256 + threadIdx.x;  // 0..524287
    const int cell = i >> 4, idx = i & 15;
    const int p = idx >> 2, q = idx & 3;
    pose_t[(cell << 4) + (q << 2) + p] = pose[i];
  } else {
    const int i = (blockIdx.x - 2048) * 256 + threadIdx.x;  // 0..36863
    const int ko = i >> 4, q = (i >> 2) & 3, r = i & 3;
    wt[(ko << 4) + (r << 2) + q] = w[i];
  }
}

// One BLOCK (512 thr, 8 waves) per TWO patches; each w4 load feeds both patches.
// Wave wv owns ci in {2wv,2wv+1} across all 9 kk. lane = o*4 + r; dims d = p*4+r.
// MODE 0: rr uniform -> z. MODE 1: rr softmax -> z. MODE 2: rr softmax -> outputs.
template <int MODE>
__global__ __launch_bounds__(512, 8) void caps_main(
    const float* __restrict__ pose_t, const float* __restrict__ act,
    const float* __restrict__ wt, const float* __restrict__ beta_a,
    const float* __restrict__ beta_v, const float* __restrict__ zin,
    const float* __restrict__ gmax, const float* __restrict__ gden,
    float* __restrict__ zout, float* __restrict__ out) {
  constexpr int S = (MODE == 0) ? K2CI_ : NV_;
  // smem layout: rrA[S] | rrB[S] | comb[4608] (partv 4x512 f2 + partr 512; prologue
  // aliases gm/ad here) | sfin 4x64 f2 (512) | sfr[64]
  __shared__ float smem[2 * S + 4608 + 576];
  float* rrA = smem;
  float* rrB = smem + S;
  float* comb = smem + 2 * S;
  f2* partv = (f2*)comb;             // [4][512]
  float* partr = comb + 4096;        // [512]
  f2* sfin = (f2*)(comb + 4608);     // [4][64]
  float* sfr = comb + 4608 + 512;    // [64]

  const int tid = threadIdx.x;
  const int wv = __builtin_amdgcn_readfirstlane(tid >> 6);
  const int l = tid & 63;
  const int o = l >> 2, r = l & 3;
  const int pid0 = blockIdx.x * 2;
  const int bA = pid0 / P2_, p2A = pid0 - bA * P2_;
  const int piA = p2A / P_, pjA = p2A - piA * P_;
  const int pid1 = pid0 + 1;
  const int bB = pid1 / P2_, p2B = pid1 - bB * P2_;
  const int piB = p2B / P_, pjB = p2B - piB * P_;
  const float inv_temp = (MODE == 0) ? 0.0005f : (MODE == 1) ? 0.000975f : 0.00142625f;

  // ---- prologue: stage rr for both patches ----
  if (MODE == 0) {
    if (tid < 288) {
      const int pp = tid >= 144;
      const int idx = pp ? tid - 144 : tid;
      const int ci = idx & 15, kk = idx >> 4;
      const int ki = (kk >= 6) ? 2 : (kk >= 3) ? 1 : 0, kj = kk - 3 * ki;
      const int b = pp ? bB : bA, pi = pp ? piB : piA, pj = pp ? pjB : pjA;
      const int cidx = ((b * H_ + pi + ki) * H_ + pj + kj) * CI_ + ci;
      (pp ? rrB : rrA)[idx] = act[cidx] / (16.0f * cnt1(pi + ki) * cnt1(pj + kj));
    }
  } else {
    if (tid < 288) {
      const int pp = tid >= 144;
      const int idx = pp ? tid - 144 : tid;
      const int ci = idx & 15, kk = idx >> 4;
      const int ki = (kk >= 6) ? 2 : (kk >= 3) ? 1 : 0, kj = kk - 3 * ki;
      const int b = pp ? bB : bA, pi = pp ? piB : piA, pj = pp ? pjB : pjA;
      const int cidx = ((b * H_ + pi + ki) * H_ + pj + kj) * CI_ + ci;
      comb[pp * 288 + idx] = gmax[cidx];
      comb[pp * 288 + 144 + idx] = act[cidx] / (gden[cidx] + EPS_);
    }
    __syncthreads();
    for (int t = tid; t < 1152; t += 512) {
      const int pp = t >= 576;
      const int i4 = pp ? t - 576 : t;
      const float4 z4 = ((const float4*)(zin + (size_t)(pid0 + pp) * NV_))[i4];
      const int k = i4 >> 2;
      const float gmk = comb[pp * 288 + k], adk = comb[pp * 288 + 144 + k];
      float4 r4;
      r4.x = __expf(z4.x - gmk) * adk;
      r4.y = __expf(z4.y - gmk) * adk;
      r4.z = __expf(z4.z - gmk) * adk;
      r4.w = __expf(z4.w - gmk) * adk;
      ((float4*)(pp ? rrB : rrA))[i4] = r4;
    }
  }
  __syncthreads();

  const float bvo = 16.0f * beta_v[o];
  const float bao = beta_a[o];
  const int ci0 = wv * 2;

  const float* wtw = wt + (l << 2) + (ci0 << 8);
  const float* pbA = pose_t + ((size_t)((bA * H_ + piA) * H_ + pjA) << 8) + (ci0 << 4);
  const float* pbB = pose_t + ((size_t)((bB * H_ + piB) * H_ + pjB) << 8) + (ci0 << 4);
  const int rb1 = (ci0 << 4) + o;  // MODE1/2 rr base
  // per-idx (idx = kk*2 + c): wt off = (kk<<12)+(c<<8); pose off = ((kk/3)<<12)+((kk%3)<<8)+(c<<4)
#define WT_OFF(idx) ((((idx) >> 1) << 12) + (((idx)&1) << 8))
#define PB_OFF(idx) (((((idx) >> 1) / 3) << 12) + ((((idx) >> 1) % 3) << 8) + (((idx)&1) << 4))
#define RR_OFF0(idx) ((((idx) >> 1) << 4) + ((idx)&1))
#define RR_OFF1(idx) ((((idx) >> 1) << 8) + (((idx)&1) << 4))

#define VOTE(pb, w4, v01, v23)                                              \
  {                                                                         \
    const float4 P0 = *(const float4*)(pb);                                 \
    const float4 P1 = *(const float4*)((pb) + 4);                           \
    const float4 P2 = *(const float4*)((pb) + 8);                           \
    const float4 P3 = *(const float4*)((pb) + 12);                          \
    v01 = (f2){P0.x, P0.y} * (w4).x;                                        \
    v23 = (f2){P0.z, P0.w} * (w4).x;                                        \
    v01 = __builtin_elementwise_fma((f2){P1.x, P1.y}, (f2){(w4).y, (w4).y}, v01); \
    v23 = __builtin_elementwise_fma((f2){P1.z, P1.w}, (f2){(w4).y, (w4).y}, v23); \
    v01 = __builtin_elementwise_fma((f2){P2.x, P2.y}, (f2){(w4).z, (w4).z}, v01); \
    v23 = __builtin_elementwise_fma((f2){P2.z, P2.w}, (f2){(w4).z, (w4).z}, v23); \
    v01 = __builtin_elementwise_fma((f2){P3.x, P3.y}, (f2){(w4).w, (w4).w}, v01); \
    v23 = __builtin_elementwise_fma((f2){P3.z, P3.w}, (f2){(w4).w, (w4).w}, v23); \
  }

  // ---- pass 1: both patches share each w4 load ----
  float prrA = 0.f, prrB = 0.f;
  const f2 zz = {0.f, 0.f};
  f2 pm01A = zz, pm23A = zz, pv01A = zz, pv23A = zz;
  f2 pm01B = zz, pm23B = zz, pv01B = zz, pv23B = zz;
#pragma unroll
  for (int idx = 0; idx < 18; ++idx) {
    const float4 w4 = *(const float4*)(wtw + WT_OFF(idx));
    f2 v01, v23;
    VOTE(pbA + PB_OFF(idx), w4, v01, v23);
    {
      const float rrk = (MODE == 0) ? rrA[ci0 + RR_OFF0(idx)] : rrA[rb1 + RR_OFF1(idx)];
      prrA += rrk;
      const f2 rr2 = {rrk, rrk};
      const f2 a01 = rr2 * v01, a23 = rr2 * v23;
      pm01A += a01; pm23A += a23;
      pv01A = __builtin_elementwise_fma(a01, v01, pv01A);
      pv23A = __builtin_elementwise_fma(a23, v23, pv23A);
    }
    VOTE(pbB + PB_OFF(idx), w4, v01, v23);
    {
      const float rrk = (MODE == 0) ? rrB[ci0 + RR_OFF0(idx)] : rrB[rb1 + RR_OFF1(idx)];
      prrB += rrk;
      const f2 rr2 = {rrk, rrk};
      const f2 a01 = rr2 * v01, a23 = rr2 * v23;
      pm01B += a01; pm23B += a23;
      pv01B = __builtin_elementwise_fma(a01, v01, pv01B);
      pv23B = __builtin_elementwise_fma(a23, v23, pv23B);
    }
  }

  // ---- combine + stats, patch A then patch B through the same buffers ----
  f2 m01[2], m23[2], va01[2], va23[2];
  float rsum[2], slvv[2], ajv[2];
#pragma unroll
  for (int pp = 0; pp < 2; ++pp) {
    partv[0 * 512 + tid] = pp ? pm01B : pm01A;
    partv[1 * 512 + tid] = pp ? pm23B : pm23A;
    partv[2 * 512 + tid] = pp ? pv01B : pv01A;
    partv[3 * 512 + tid] = pp ? pv23B : pv23A;
    partr[tid] = pp ? prrB : prrA;
    __syncthreads();
    if (tid < 320) {
      if (tid < 256) {
        const int st = tid >> 6, li = tid & 63;
        f2 acc = partv[st * 512 + li];
#pragma unroll
        for (int wvi = 1; wvi < 8; ++wvi) acc += partv[st * 512 + wvi * 64 + li];
        sfin[st * 64 + li] = acc;
      } else {
        const int li = tid & 63;
        float acc = partr[li];
#pragma unroll
        for (int wvi = 1; wvi < 8; ++wvi) acc += partr[wvi * 64 + li];
        sfr[li] = acc;
      }
    }
    __syncthreads();
    const f2 S01 = sfin[0 * 64 + l], S23 = sfin[1 * 64 + l];
    const f2 V01 = sfin[2 * 64 + l], V23 = sfin[3 * 64 + l];
    const float rs = sfr[l] + EPS_;
    const float irs = 1.0f / rs;
    const f2 irs2 = {irs, irs};
    const f2 mm01 = S01 * irs2, mm23 = S23 * irs2;
    const f2 eps2 = {EPS_, EPS_};
    const f2 vv01 = __builtin_elementwise_max(V01 * irs2 - mm01 * mm01, zz) + eps2;
    const f2 vv23 = __builtin_elementwise_max(V23 * irs2 - mm23 * mm23, zz) + eps2;
    float slv = __logf(vv01.x) + __logf(vv01.y) + __logf(vv23.x) + __logf(vv23.y);
    slv += __shfl_xor(slv, 1);
    slv += __shfl_xor(slv, 2);
    const float cost = (bvo + 0.5f * slv) * rs;
    const float aj = 1.0f / (1.0f + __expf(-inv_temp * (bao - cost)));
    m01[pp] = mm01; m23[pp] = mm23; va01[pp] = vv01; va23[pp] = vv23;
    rsum[pp] = rs; slvv[pp] = slv; ajv[pp] = aj;
    if (pp == 0) __syncthreads();  // protect sfin/sfr before reuse for B
  }

  if (MODE == 2) {
    if (wv < 2) {  // wave 0 -> patch A, wave 1 -> patch B
      const int pp = wv;
      float* ob = out + ((size_t)((pid0 + pp) * 16 + o) << 4) + r;
      ob[0] = m01[pp].x; ob[4] = m01[pp].y; ob[8] = m23[pp].x; ob[12] = m23[pp].y;
      if (r == 0) out[(size_t)B_ * P2_ * O_ * 16 + (pid0 + pp) * 16 + o] = ajv[pp];
    }
    return;
  }

  // ---- pass 2: recompute votes for both patches, write z[k][o] ----
  const f2 iv01A = {1.0f / va01[0].x, 1.0f / va01[0].y};
  const f2 iv23A = {1.0f / va23[0].x, 1.0f / va23[0].y};
  const f2 iv01B = {1.0f / va01[1].x, 1.0f / va01[1].y};
  const f2 iv23B = {1.0f / va23[1].x, 1.0f / va23[1].y};
  const float CzA = __logf(ajv[0] + EPS_) - 0.5f * (slvv[0] + 16.0f * LOG2PI_);
  const float CzB = __logf(ajv[1] + EPS_) - 0.5f * (slvv[1] + 16.0f * LOG2PI_);
  // z flat offset for (k = kk*16 + ci0 + c, o): (kk<<8) + ((ci0+c)<<4) + o
  // base carries (ci0<<4) + o ; RR_OFF1 supplies (kk<<8) + (c<<4).   [bugfix vs r11]
  float* zoA = zout + (size_t)pid0 * NV_ + (ci0 << 4) + o;
  float* zoB = zoA + NV_;
#pragma unroll
  for (int idx = 0; idx < 18; ++idx) {
    const float4 w4 = *(const float4*)(wtw + WT_OFF(idx));
    f2 vA01, vA23, vB01, vB23;
    VOTE(pbA + PB_OFF(idx), w4, vA01, vA23);
    VOTE(pbB + PB_OFF(idx), w4, vB01, vB23);
    const f2 dA01 = vA01 - m01[0], dA23 = vA23 - m23[0];
    const f2 dB01 = vB01 - m01[1], dB23 = vB23 - m23[1];
    const f2 qa2 = __builtin_elementwise_fma(dA01 * dA01, iv01A, (dA23 * dA23) * iv23A);
    const f2 qb2 = __builtin_elementwise_fma(dB01 * dB01, iv01B, (dB23 * dB23) * iv23B);
    float qa = qa2.x + qa2.y, qb = qb2.x + qb2.y;
    qa += __shfl_xor(qa, 1);
    qb += __shfl_xor(qb, 1);
    qa += __shfl_xor(qa, 2);
    qb += __shfl_xor(qb, 2);
    if (r == 0) {
      zoA[RR_OFF1(idx)] = CzA - 0.5f * qa;  // 16 lanes -> one 64B line
      zoB[RR_OFF1(idx)] = CzB - 0.5f * qb;
    }
  }
#undef WT_OFF
#undef PB_OFF
#undef RR_OFF0
#undef RR_OFF1
#undef VOTE
}

// 4 threads per segment (b,h,w,ci); z cached in registers between max and sum.
__global__ __launch_bounds__(256) void seg_reduce(const float* __restrict__ z,
                                                  float* __restrict__ gmax,
                                                  float* __restrict__ gden) {
  const int tid = blockIdx.x * 256 + threadIdx.x;  // 0..131071
  const int part = tid & 3, ci = (tid >> 2) & 15, w2 = (tid >> 6) & 15;
  const int h = (tid >> 10) & 15, b = tid >> 14;
  float4 v[9];
  float m = -3.0e38f;
#pragma unroll
  for (int s = 0; s < 9; ++s) {
    const int ki = (s >= 6) ? 2 : (s >= 3) ? 1 : 0, kj = s - 3 * ki;
    const int pi = h - ki, pj = w2 - kj;
    if ((unsigned)pi < (unsigned)P_ && (unsigned)pj < (unsigned)P_) {
      v[s] = *(const float4*)(z + (size_t)(b * P2_ + pi * P_ + pj) * NV_ + s * 256 +
                              ci * 16 + part * 4);
    } else {
      v[s] = make_float4(-3.0e38f, -3.0e38f, -3.0e38f, -3.0e38f);
    }
    m = fmaxf(m, fmaxf(fmaxf(v[s].x, v[s].y), fmaxf(v[s].z, v[s].w)));
  }
  m = fmaxf(m, __shfl_xor(m, 1));
  m = fmaxf(m, __shfl_xor(m, 2));
  float s_ = 0.f;
#pragma unroll
  for (int s = 0; s < 9; ++s) {
    s_ += __expf(v[s].x - m) + __expf(v[s].y - m) + __expf(v[s].z - m) + __expf(v[s].w - m);
  }
  s_ += __shfl_xor(s_, 1);
  s_ += __shfl_xor(s_, 2);
  if (part == 0) {
    gmax[tid >> 2] = m;
    gden[tid >> 2] = s_;
  }
}
}  // namespace

extern "C" void kernel_launch(void* const* d_in, const int* in_sizes, int n_in,
                              void* d_out, int out_size, void* d_ws, size_t ws_size,
                              hipStream_t stream) {
  const float* pose = (const float*)d_in[0];
  const float* act = (const float*)d_in[1];
  const float* w = (const float*)d_in[2];
  const float* ba = (const float*)d_in[3];
  const float* bv = (const float*)d_in[4];
  float* out = (float*)d_out;

  float* z = (float*)d_ws;                  // 3,612,672 floats, layout [pid][k][o]
  float* gm = z + (size_t)B_ * P2_ * NV_;   // 32,768
  float* gd = gm + B_ * H_ * H_ * CI_;      // 32,768
  float* wt = gd + B_ * H_ * H_ * CI_;      // 36,864
  float* pt = wt + 36864;                   // 524,288 (pose transposed)

  const int NB = B_ * P2_ / 2;  // 784 blocks, two patches each
  transpose_all<<<2192, 256, 0, stream>>>(pose, pt, w, wt);
  caps_main<0><<<NB, 512, 0, stream>>>(pt, act, wt, ba, bv, z, gm, gd, z, out);
  seg_reduce<<<512, 256, 0, stream>>>(z, gm, gd);
  caps_main<1><<<NB, 512, 0, stream>>>(pt, act, wt, ba, bv, z, gm, gd, z, out);
  seg_reduce<<<512, 256, 0, stream>>>(z, gm, gd);
  caps_main<2><<<NB, 512, 0, stream>>>(pt, act, wt, ba, bv, z, gm, gd, z, out);
}

// Round 13
// 182.011 us; speedup vs baseline: 1.3750x; 1.3750x over previous
//
#include <hip/hip_runtime.h>

namespace {
constexpr int B_ = 8, H_ = 16, CI_ = 16, O_ = 16, P_ = 14;
constexpr int P2_ = P_ * P_;    // 196
constexpr int K2CI_ = 144;
constexpr int NV_ = 2304;       // z per patch, layout [k][o]
constexpr float EPS_ = 1e-9f;
constexpr float LOG2PI_ = 1.8378770664093453f;

using f2 = __attribute__((ext_vector_type(2))) float;

__device__ __forceinline__ float cnt1(int h) {
  int lo = (h - (P_ - 1)) > 0 ? (h - (P_ - 1)) : 0;
  int hi = h < 2 ? h : 2;
  return (float)(hi - lo + 1);
}

// Fused prologue: blocks [0,2048) transpose pose (4x4 per cell -> [q][p]);
// blocks [2048,2192) transpose w -> wt[k][o][r][q].
__global__ __launch_bounds__(256) void transpose_all(const float* __restrict__ pose,
                                                     float* __restrict__ pose_t,
                                                     const float* __restrict__ w,
                                                     float* __restrict__ wt) {
  if (blockIdx.x < 2048) {
    const int i = blockIdx.x * 256 + threadIdx.x;  // 0..524287
    const int cell = i >> 4, idx = i & 15;
    const int p = idx >> 2, q = idx & 3;
    pose_t[(cell << 4) + (q << 2) + p] = pose[i];
  } else {
    const int i = (blockIdx.x - 2048) * 256 + threadIdx.x;  // 0..36863
    const int ko = i >> 4, q = (i >> 2) & 3, r = i & 3;
    wt[(ko << 4) + (r << 2) + q] = w[i];
  }
}

// One BLOCK (512 thr, 8 waves) per TWO patches; each w4 load feeds both patches.
// Wave wv owns ci in {2wv,2wv+1} across all 9 kk. lane = o*4 + r; dims d = p*4+r.
// __launch_bounds__(512,4): 128-VGPR budget -> no scratch spill (r12 lesson).
// MODE 0: rr uniform -> z. MODE 1: rr softmax -> z. MODE 2: rr softmax -> outputs.
template <int MODE>
__global__ __launch_bounds__(512, 4) void caps_main(
    const float* __restrict__ pose_t, const float* __restrict__ act,
    const float* __restrict__ wt, const float* __restrict__ beta_a,
    const float* __restrict__ beta_v, const float* __restrict__ zin,
    const float* __restrict__ gmax, const float* __restrict__ gden,
    float* __restrict__ zout, float* __restrict__ out) {
  constexpr int S = (MODE == 0) ? K2CI_ : NV_;
  // smem layout: rrA[S] | rrB[S] | comb[4608] (partv 4x512 f2 + partr 512; prologue
  // aliases gm/ad here) | sfin 4x64 f2 (512) | sfr[64]
  __shared__ float smem[2 * S + 4608 + 576];
  float* rrA = smem;
  float* rrB = smem + S;
  float* comb = smem + 2 * S;
  f2* partv = (f2*)comb;             // [4][512]
  float* partr = comb + 4096;        // [512]
  f2* sfin = (f2*)(comb + 4608);     // [4][64]
  float* sfr = comb + 4608 + 512;    // [64]

  const int tid = threadIdx.x;
  const int wv = __builtin_amdgcn_readfirstlane(tid >> 6);
  const int l = tid & 63;
  const int o = l >> 2, r = l & 3;
  const int pid0 = blockIdx.x * 2;
  const int bA = pid0 / P2_, p2A = pid0 - bA * P2_;
  const int piA = p2A / P_, pjA = p2A - piA * P_;
  const int pid1 = pid0 + 1;
  const int bB = pid1 / P2_, p2B = pid1 - bB * P2_;
  const int piB = p2B / P_, pjB = p2B - piB * P_;
  const float inv_temp = (MODE == 0) ? 0.0005f : (MODE == 1) ? 0.000975f : 0.00142625f;

  // ---- prologue: stage rr for both patches ----
  if (MODE == 0) {
    if (tid < 288) {
      const int pp = tid >= 144;
      const int idx = pp ? tid - 144 : tid;
      const int ci = idx & 15, kk = idx >> 4;
      const int ki = (kk >= 6) ? 2 : (kk >= 3) ? 1 : 0, kj = kk - 3 * ki;
      const int b = pp ? bB : bA, pi = pp ? piB : piA, pj = pp ? pjB : pjA;
      const int cidx = ((b * H_ + pi + ki) * H_ + pj + kj) * CI_ + ci;
      (pp ? rrB : rrA)[idx] = act[cidx] / (16.0f * cnt1(pi + ki) * cnt1(pj + kj));
    }
  } else {
    if (tid < 288) {
      const int pp = tid >= 144;
      const int idx = pp ? tid - 144 : tid;
      const int ci = idx & 15, kk = idx >> 4;
      const int ki = (kk >= 6) ? 2 : (kk >= 3) ? 1 : 0, kj = kk - 3 * ki;
      const int b = pp ? bB : bA, pi = pp ? piB : piA, pj = pp ? pjB : pjA;
      const int cidx = ((b * H_ + pi + ki) * H_ + pj + kj) * CI_ + ci;
      comb[pp * 288 + idx] = gmax[cidx];
      comb[pp * 288 + 144 + idx] = act[cidx] / (gden[cidx] + EPS_);
    }
    __syncthreads();
    for (int t = tid; t < 1152; t += 512) {
      const int pp = t >= 576;
      const int i4 = pp ? t - 576 : t;
      const float4 z4 = ((const float4*)(zin + (size_t)(pid0 + pp) * NV_))[i4];
      const int k = i4 >> 2;
      const float gmk = comb[pp * 288 + k], adk = comb[pp * 288 + 144 + k];
      float4 r4;
      r4.x = __expf(z4.x - gmk) * adk;
      r4.y = __expf(z4.y - gmk) * adk;
      r4.z = __expf(z4.z - gmk) * adk;
      r4.w = __expf(z4.w - gmk) * adk;
      ((float4*)(pp ? rrB : rrA))[i4] = r4;
    }
  }
  __syncthreads();

  const float bvo = 16.0f * beta_v[o];
  const float bao = beta_a[o];
  const int ci0 = wv * 2;

  const float* wtw = wt + (l << 2) + (ci0 << 8);
  const float* pbA = pose_t + ((size_t)((bA * H_ + piA) * H_ + pjA) << 8) + (ci0 << 4);
  const float* pbB = pose_t + ((size_t)((bB * H_ + piB) * H_ + pjB) << 8) + (ci0 << 4);
  const int rb1 = (ci0 << 4) + o;  // MODE1/2 rr base
  // per-idx (idx = kk*2 + c): wt off = (kk<<12)+(c<<8); pose off = ((kk/3)<<12)+((kk%3)<<8)+(c<<4)
#define WT_OFF(idx) ((((idx) >> 1) << 12) + (((idx)&1) << 8))
#define PB_OFF(idx) (((((idx) >> 1) / 3) << 12) + ((((idx) >> 1) % 3) << 8) + (((idx)&1) << 4))
#define RR_OFF0(idx) ((((idx) >> 1) << 4) + ((idx)&1))
#define RR_OFF1(idx) ((((idx) >> 1) << 8) + (((idx)&1) << 4))

#define VOTE(pb, w4, v01, v23)                                              \
  {                                                                         \
    const float4 P0 = *(const float4*)(pb);                                 \
    const float4 P1 = *(const float4*)((pb) + 4);                           \
    const float4 P2 = *(const float4*)((pb) + 8);                           \
    const float4 P3 = *(const float4*)((pb) + 12);                          \
    v01 = (f2){P0.x, P0.y} * (w4).x;                                        \
    v23 = (f2){P0.z, P0.w} * (w4).x;                                        \
    v01 = __builtin_elementwise_fma((f2){P1.x, P1.y}, (f2){(w4).y, (w4).y}, v01); \
    v23 = __builtin_elementwise_fma((f2){P1.z, P1.w}, (f2){(w4).y, (w4).y}, v23); \
    v01 = __builtin_elementwise_fma((f2){P2.x, P2.y}, (f2){(w4).z, (w4).z}, v01); \
    v23 = __builtin_elementwise_fma((f2){P2.z, P2.w}, (f2){(w4).z, (w4).z}, v23); \
    v01 = __builtin_elementwise_fma((f2){P3.x, P3.y}, (f2){(w4).w, (w4).w}, v01); \
    v23 = __builtin_elementwise_fma((f2){P3.z, P3.w}, (f2){(w4).w, (w4).w}, v23); \
  }

  // ---- pass 1: both patches share each w4 load ----
  float prrA = 0.f, prrB = 0.f;
  const f2 zz = {0.f, 0.f};
  f2 pm01A = zz, pm23A = zz, pv01A = zz, pv23A = zz;
  f2 pm01B = zz, pm23B = zz, pv01B = zz, pv23B = zz;
#pragma unroll
  for (int idx = 0; idx < 18; ++idx) {
    const float4 w4 = *(const float4*)(wtw + WT_OFF(idx));
    f2 v01, v23;
    VOTE(pbA + PB_OFF(idx), w4, v01, v23);
    {
      const float rrk = (MODE == 0) ? rrA[ci0 + RR_OFF0(idx)] : rrA[rb1 + RR_OFF1(idx)];
      prrA += rrk;
      const f2 rr2 = {rrk, rrk};
      const f2 a01 = rr2 * v01, a23 = rr2 * v23;
      pm01A += a01; pm23A += a23;
      pv01A = __builtin_elementwise_fma(a01, v01, pv01A);
      pv23A = __builtin_elementwise_fma(a23, v23, pv23A);
    }
    VOTE(pbB + PB_OFF(idx), w4, v01, v23);
    {
      const float rrk = (MODE == 0) ? rrB[ci0 + RR_OFF0(idx)] : rrB[rb1 + RR_OFF1(idx)];
      prrB += rrk;
      const f2 rr2 = {rrk, rrk};
      const f2 a01 = rr2 * v01, a23 = rr2 * v23;
      pm01B += a01; pm23B += a23;
      pv01B = __builtin_elementwise_fma(a01, v01, pv01B);
      pv23B = __builtin_elementwise_fma(a23, v23, pv23B);
    }
  }

  // ---- combine + stats, patch A then patch B through the same buffers ----
  f2 m01[2], m23[2], va01[2], va23[2];
  float rsum[2], slvv[2], ajv[2];
#pragma unroll
  for (int pp = 0; pp < 2; ++pp) {
    partv[0 * 512 + tid] = pp ? pm01B : pm01A;
    partv[1 * 512 + tid] = pp ? pm23B : pm23A;
    partv[2 * 512 + tid] = pp ? pv01B : pv01A;
    partv[3 * 512 + tid] = pp ? pv23B : pv23A;
    partr[tid] = pp ? prrB : prrA;
    __syncthreads();
    if (tid < 320) {
      if (tid < 256) {
        const int st = tid >> 6, li = tid & 63;
        f2 acc = partv[st * 512 + li];
#pragma unroll
        for (int wvi = 1; wvi < 8; ++wvi) acc += partv[st * 512 + wvi * 64 + li];
        sfin[st * 64 + li] = acc;
      } else {
        const int li = tid & 63;
        float acc = partr[li];
#pragma unroll
        for (int wvi = 1; wvi < 8; ++wvi) acc += partr[wvi * 64 + li];
        sfr[li] = acc;
      }
    }
    __syncthreads();
    const f2 S01 = sfin[0 * 64 + l], S23 = sfin[1 * 64 + l];
    const f2 V01 = sfin[2 * 64 + l], V23 = sfin[3 * 64 + l];
    const float rs = sfr[l] + EPS_;
    const float irs = 1.0f / rs;
    const f2 irs2 = {irs, irs};
    const f2 mm01 = S01 * irs2, mm23 = S23 * irs2;
    const f2 eps2 = {EPS_, EPS_};
    const f2 vv01 = __builtin_elementwise_max(V01 * irs2 - mm01 * mm01, zz) + eps2;
    const f2 vv23 = __builtin_elementwise_max(V23 * irs2 - mm23 * mm23, zz) + eps2;
    float slv = __logf(vv01.x) + __logf(vv01.y) + __logf(vv23.x) + __logf(vv23.y);
    slv += __shfl_xor(slv, 1);
    slv += __shfl_xor(slv, 2);
    const float cost = (bvo + 0.5f * slv) * rs;
    const float aj = 1.0f / (1.0f + __expf(-inv_temp * (bao - cost)));
    m01[pp] = mm01; m23[pp] = mm23; va01[pp] = vv01; va23[pp] = vv23;
    rsum[pp] = rs; slvv[pp] = slv; ajv[pp] = aj;
    if (pp == 0) __syncthreads();  // protect sfin/sfr before reuse for B
  }

  if (MODE == 2) {
    if (wv < 2) {  // wave 0 -> patch A, wave 1 -> patch B
      const int pp = wv;
      float* ob = out + ((size_t)((pid0 + pp) * 16 + o) << 4) + r;
      ob[0] = m01[pp].x; ob[4] = m01[pp].y; ob[8] = m23[pp].x; ob[12] = m23[pp].y;
      if (r == 0) out[(size_t)B_ * P2_ * O_ * 16 + (pid0 + pp) * 16 + o] = ajv[pp];
    }
    return;
  }

  // ---- pass 2: recompute votes for both patches, write z[k][o] ----
  const f2 iv01A = {1.0f / va01[0].x, 1.0f / va01[0].y};
  const f2 iv23A = {1.0f / va23[0].x, 1.0f / va23[0].y};
  const f2 iv01B = {1.0f / va01[1].x, 1.0f / va01[1].y};
  const f2 iv23B = {1.0f / va23[1].x, 1.0f / va23[1].y};
  const float CzA = __logf(ajv[0] + EPS_) - 0.5f * (slvv[0] + 16.0f * LOG2PI_);
  const float CzB = __logf(ajv[1] + EPS_) - 0.5f * (slvv[1] + 16.0f * LOG2PI_);
  // z flat offset for (k = kk*16 + ci0 + c, o): (kk<<8) + ((ci0+c)<<4) + o
  float* zoA = zout + (size_t)pid0 * NV_ + (ci0 << 4) + o;
  float* zoB = zoA + NV_;
#pragma unroll
  for (int idx = 0; idx < 18; ++idx) {
    const float4 w4 = *(const float4*)(wtw + WT_OFF(idx));
    f2 vA01, vA23, vB01, vB23;
    VOTE(pbA + PB_OFF(idx), w4, vA01, vA23);
    VOTE(pbB + PB_OFF(idx), w4, vB01, vB23);
    const f2 dA01 = vA01 - m01[0], dA23 = vA23 - m23[0];
    const f2 dB01 = vB01 - m01[1], dB23 = vB23 - m23[1];
    const f2 qa2 = __builtin_elementwise_fma(dA01 * dA01, iv01A, (dA23 * dA23) * iv23A);
    const f2 qb2 = __builtin_elementwise_fma(dB01 * dB01, iv01B, (dB23 * dB23) * iv23B);
    float qa = qa2.x + qa2.y, qb = qb2.x + qb2.y;
    qa += __shfl_xor(qa, 1);
    qb += __shfl_xor(qb, 1);
    qa += __shfl_xor(qa, 2);
    qb += __shfl_xor(qb, 2);
    if (r == 0) {
      zoA[RR_OFF1(idx)] = CzA - 0.5f * qa;  // 16 lanes -> one 64B line
      zoB[RR_OFF1(idx)] = CzB - 0.5f * qb;
    }
  }
#undef WT_OFF
#undef PB_OFF
#undef RR_OFF0
#undef RR_OFF1
#undef VOTE
}

// 4 threads per segment (b,h,w,ci); z cached in registers between max and sum.
__global__ __launch_bounds__(256) void seg_reduce(const float* __restrict__ z,
                                                  float* __restrict__ gmax,
                                                  float* __restrict__ gden) {
  const int tid = blockIdx.x * 256 + threadIdx.x;  // 0..131071
  const int part = tid & 3, ci = (tid >> 2) & 15, w2 = (tid >> 6) & 15;
  const int h = (tid >> 10) & 15, b = tid >> 14;
  float4 v[9];
  float m = -3.0e38f;
#pragma unroll
  for (int s = 0; s < 9; ++s) {
    const int ki = (s >= 6) ? 2 : (s >= 3) ? 1 : 0, kj = s - 3 * ki;
    const int pi = h - ki, pj = w2 - kj;
    if ((unsigned)pi < (unsigned)P_ && (unsigned)pj < (unsigned)P_) {
      v[s] = *(const float4*)(z + (size_t)(b * P2_ + pi * P_ + pj) * NV_ + s * 256 +
                              ci * 16 + part * 4);
    } else {
      v[s] = make_float4(-3.0e38f, -3.0e38f, -3.0e38f, -3.0e38f);
    }
    m = fmaxf(m, fmaxf(fmaxf(v[s].x, v[s].y), fmaxf(v[s].z, v[s].w)));
  }
  m = fmaxf(m, __shfl_xor(m, 1));
  m = fmaxf(m, __shfl_xor(m, 2));
  float s_ = 0.f;
#pragma unroll
  for (int s = 0; s < 9; ++s) {
    s_ += __expf(v[s].x - m) + __expf(v[s].y - m) + __expf(v[s].z - m) + __expf(v[s].w - m);
  }
  s_ += __shfl_xor(s_, 1);
  s_ += __shfl_xor(s_, 2);
  if (part == 0) {
    gmax[tid >> 2] = m;
    gden[tid >> 2] = s_;
  }
}
}  // namespace

extern "C" void kernel_launch(void* const* d_in, const int* in_sizes, int n_in,
                              void* d_out, int out_size, void* d_ws, size_t ws_size,
                              hipStream_t stream) {
  const float* pose = (const float*)d_in[0];
  const float* act = (const float*)d_in[1];
  const float* w = (const float*)d_in[2];
  const float* ba = (const float*)d_in[3];
  const float* bv = (const float*)d_in[4];
  float* out = (float*)d_out;

  float* z = (float*)d_ws;                  // 3,612,672 floats, layout [pid][k][o]
  float* gm = z + (size_t)B_ * P2_ * NV_;   // 32,768
  float* gd = gm + B_ * H_ * H_ * CI_;      // 32,768
  float* wt = gd + B_ * H_ * H_ * CI_;      // 36,864
  float* pt = wt + 36864;                   // 524,288 (pose transposed)

  const int NB = B_ * P2_ / 2;  // 784 blocks, two patches each
  transpose_all<<<2192, 256, 0, stream>>>(pose, pt, w, wt);
  caps_main<0><<<NB, 512, 0, stream>>>(pt, act, wt, ba, bv, z, gm, gd, z, out);
  seg_reduce<<<512, 256, 0, stream>>>(z, gm, gd);
  caps_main<1><<<NB, 512, 0, stream>>>(pt, act, wt, ba, bv, z, gm, gd, z, out);
  seg_reduce<<<512, 256, 0, stream>>>(z, gm, gd);
  caps_main<2><<<NB, 512, 0, stream>>>(pt, act, wt, ba, bv, z, gm, gd, z, out);
}

// Round 14
// 167.753 us; speedup vs baseline: 1.4919x; 1.0850x over previous
//
#include <hip/hip_runtime.h>

namespace {
constexpr int B_ = 8, H_ = 16, CI_ = 16, O_ = 16, P_ = 14;
constexpr int P2_ = P_ * P_;    // 196
constexpr int K2CI_ = 144;
constexpr int NV_ = 2304;       // z per patch, layout [k][o]
constexpr float EPS_ = 1e-9f;
constexpr float LOG2PI_ = 1.8378770664093453f;

using f2 = __attribute__((ext_vector_type(2))) float;

__device__ __forceinline__ float cnt1(int h) {
  int lo = (h - (P_ - 1)) > 0 ? (h - (P_ - 1)) : 0;
  int hi = h < 2 ? h : 2;
  return (float)(hi - lo + 1);
}

// Fused prologue: blocks [0,2048) transpose pose (4x4 per cell -> [q][p]);
// blocks [2048,2192) transpose w -> wt[k][o][r][q].
__global__ __launch_bounds__(256) void transpose_all(const float* __restrict__ pose,
                                                     float* __restrict__ pose_t,
                                                     const float* __restrict__ w,
                                                     float* __restrict__ wt) {
  if (blockIdx.x < 2048) {
    const int i = blockIdx.x * 256 + threadIdx.x;  // 0..524287
    const int cell = i >> 4, idx = i & 15;
    const int p = idx >> 2, q = idx & 3;
    pose_t[(cell << 4) + (q << 2) + p] = pose[i];
  } else {
    const int i = (blockIdx.x - 2048) * 256 + threadIdx.x;  // 0..36863
    const int ko = i >> 4, q = (i >> 2) & 3, r = i & 3;
    wt[(ko << 4) + (r << 2) + q] = w[i];
  }
}

// One BLOCK (512 thr, 8 waves) per patch. Wave wv owns ci in {2wv,2wv+1} across all 9 kk.
// lane = o*4 + r; dims d = p*4+r. Votes cached in VGPRs across the combine so pass 2
// issues ZERO loads. __launch_bounds__(512,4): 128-VGPR budget (~112 live, no spill).
// MODE 0: rr uniform -> z. MODE 1: rr softmax -> z. MODE 2: rr softmax -> outputs.
template <int MODE>
__global__ __launch_bounds__(512, 4) void caps_main(
    const float* __restrict__ pose_t, const float* __restrict__ act,
    const float* __restrict__ wt, const float* __restrict__ beta_a,
    const float* __restrict__ beta_v, const float* __restrict__ zin,
    const float* __restrict__ gmax, const float* __restrict__ gden,
    float* __restrict__ zout, float* __restrict__ out) {
  __shared__ float rr_s[(MODE == 0) ? K2CI_ : NV_];  // MODE0: rr0[k] ; else rr[k][o]
  __shared__ f2 partv[4][512];                       // pm01, pm23, pv01, pv23
  __shared__ float partr[512];                       // prr
  __shared__ f2 sfin[4][64];
  __shared__ float sfr[64];
  __shared__ float gm_s[(MODE == 0) ? 1 : K2CI_];
  __shared__ float ad_s[(MODE == 0) ? 1 : K2CI_];

  const int tid = threadIdx.x;
  const int wv = __builtin_amdgcn_readfirstlane(tid >> 6);
  const int l = tid & 63;
  const int o = l >> 2, r = l & 3;
  const int pid = blockIdx.x;
  const int b = pid / P2_;
  const int p2 = pid - b * P2_;
  const int pi = p2 / P_;
  const int pj = p2 - pi * P_;
  const float inv_temp = (MODE == 0) ? 0.0005f : (MODE == 1) ? 0.000975f : 0.00142625f;

  // ---- prologue: stage rr (or gmax/act-den) into LDS ----
  if (MODE == 0) {
    if (tid < K2CI_) {
      const int ci = tid & 15, kk = tid >> 4;
      const int ki = (kk >= 6) ? 2 : (kk >= 3) ? 1 : 0, kj = kk - 3 * ki;
      const int cidx = ((b * H_ + pi + ki) * H_ + pj + kj) * CI_ + ci;
      rr_s[tid] = act[cidx] / (16.0f * cnt1(pi + ki) * cnt1(pj + kj));
    }
  } else {
    if (tid < K2CI_) {
      const int ci = tid & 15, kk = tid >> 4;
      const int ki = (kk >= 6) ? 2 : (kk >= 3) ? 1 : 0, kj = kk - 3 * ki;
      const int cidx = ((b * H_ + pi + ki) * H_ + pj + kj) * CI_ + ci;
      gm_s[tid] = gmax[cidx];
      ad_s[tid] = act[cidx] / (gden[cidx] + EPS_);
    }
    __syncthreads();
    for (int i4 = tid; i4 < NV_ / 4; i4 += 512) {
      const float4 z4 = ((const float4*)(zin + (size_t)pid * NV_))[i4];
      const int k = i4 >> 2;
      const float gmk = gm_s[k], adk = ad_s[k];
      float4 r4;
      r4.x = __expf(z4.x - gmk) * adk;
      r4.y = __expf(z4.y - gmk) * adk;
      r4.z = __expf(z4.z - gmk) * adk;
      r4.w = __expf(z4.w - gmk) * adk;
      ((float4*)rr_s)[i4] = r4;
    }
  }
  __syncthreads();

  const float bvo = 16.0f * beta_v[o];
  const float bao = beta_a[o];
  const int ci0 = wv * 2;

  const float* pose_b = pose_t + ((size_t)((b * H_ + pi) * H_ + pj) << 8);
  const float* wt_l = wt + (l << 2);
  // idx in [0,18): kk = idx>>1, ci = ci0 + (idx&1)
#define WT_OFF(idx) ((((idx) >> 1) << 12) + ((ci0 + ((idx)&1)) << 8))
#define PB_OFF(idx) (((((idx) >> 1) / 3) << 12) + ((((idx) >> 1) % 3) << 8) + ((ci0 + ((idx)&1)) << 4))

  // ---- pass 1: packed fused mean+var partials; votes cached in VGPRs ----
  f2 vc01[18], vc23[18];
  float prr = 0.f;
  const f2 zz = {0.f, 0.f};
  f2 pm01 = zz, pm23 = zz, pv01 = zz, pv23 = zz;
#pragma unroll
  for (int idx = 0; idx < 18; ++idx) {
    const float4 w4 = *(const float4*)(wt_l + WT_OFF(idx));
    const float* pb = pose_b + PB_OFF(idx);
    const float4 P0 = *(const float4*)(pb);
    const float4 P1 = *(const float4*)(pb + 4);
    const float4 P2 = *(const float4*)(pb + 8);
    const float4 P3 = *(const float4*)(pb + 12);
    f2 v01 = (f2){P0.x, P0.y} * w4.x;
    f2 v23 = (f2){P0.z, P0.w} * w4.x;
    v01 = __builtin_elementwise_fma((f2){P1.x, P1.y}, (f2){w4.y, w4.y}, v01);
    v23 = __builtin_elementwise_fma((f2){P1.z, P1.w}, (f2){w4.y, w4.y}, v23);
    v01 = __builtin_elementwise_fma((f2){P2.x, P2.y}, (f2){w4.z, w4.z}, v01);
    v23 = __builtin_elementwise_fma((f2){P2.z, P2.w}, (f2){w4.z, w4.z}, v23);
    v01 = __builtin_elementwise_fma((f2){P3.x, P3.y}, (f2){w4.w, w4.w}, v01);
    v23 = __builtin_elementwise_fma((f2){P3.z, P3.w}, (f2){w4.w, w4.w}, v23);
    if (MODE != 2) {
      vc01[idx] = v01;
      vc23[idx] = v23;
    }
    const int k = ((idx >> 1) << 4) + ci0 + (idx & 1);
    const float rrk = (MODE == 0) ? rr_s[k] : rr_s[(k << 4) + o];
    prr += rrk;
    const f2 rr2 = {rrk, rrk};
    const f2 a01 = rr2 * v01, a23 = rr2 * v23;
    pm01 += a01;
    pm23 += a23;
    pv01 = __builtin_elementwise_fma(a01, v01, pv01);
    pv23 = __builtin_elementwise_fma(a23, v23, pv23);
  }

  // ---- two-stage cross-wave combine ----
  partv[0][tid] = pm01; partv[1][tid] = pm23;
  partv[2][tid] = pv01; partv[3][tid] = pv23;
  partr[tid] = prr;
  __syncthreads();
  if (tid < 320) {
    if (tid < 256) {
      const int st = tid >> 6, li = tid & 63;
      f2 acc = partv[st][li];
#pragma unroll
      for (int wvi = 1; wvi < 8; ++wvi) acc += partv[st][wvi * 64 + li];
      sfin[st][li] = acc;
    } else {
      const int li = tid & 63;
      float acc = partr[li];
#pragma unroll
      for (int wvi = 1; wvi < 8; ++wvi) acc += partr[wvi * 64 + li];
      sfr[li] = acc;
    }
  }
  __syncthreads();
  const f2 S01 = sfin[0][l], S23 = sfin[1][l];
  const f2 V01 = sfin[2][l], V23 = sfin[3][l];
  const float rsum = sfr[l] + EPS_;
  const float irs = 1.0f / rsum;
  const f2 irs2 = {irs, irs};
  const f2 m01 = S01 * irs2, m23 = S23 * irs2;
  const f2 eps2 = {EPS_, EPS_};
  const f2 va01 = __builtin_elementwise_max(V01 * irs2 - m01 * m01, zz) + eps2;
  const f2 va23 = __builtin_elementwise_max(V23 * irs2 - m23 * m23, zz) + eps2;
  float slv = __logf(va01.x) + __logf(va01.y) + __logf(va23.x) + __logf(va23.y);
  slv += __shfl_xor(slv, 1);
  slv += __shfl_xor(slv, 2);
  const float cost = (bvo + 0.5f * slv) * rsum;
  const float aj = 1.0f / (1.0f + __expf(-inv_temp * (bao - cost)));

  if (MODE == 2) {
    if (wv == 0) {
      float* ob = out + ((size_t)(pid * 16 + o) << 4) + r;
      ob[0] = m01.x; ob[4] = m01.y; ob[8] = m23.x; ob[12] = m23.y;
      if (r == 0) out[(size_t)B_ * P2_ * O_ * 16 + pid * 16 + o] = aj;
    }
    return;
  }

  // ---- pass 2: pure VALU from cached votes (zero loads), write z[k][o] ----
  const f2 iv01 = {1.0f / va01.x, 1.0f / va01.y};
  const f2 iv23 = {1.0f / va23.x, 1.0f / va23.y};
  const float Cz = __logf(aj + EPS_) - 0.5f * (slv + 16.0f * LOG2PI_);
  float* zo = zout + (size_t)pid * NV_ + o;
#pragma unroll
  for (int idx = 0; idx < 18; ++idx) {
    const f2 d01 = vc01[idx] - m01, d23 = vc23[idx] - m23;
    const f2 q2 = __builtin_elementwise_fma(d01 * d01, iv01, (d23 * d23) * iv23);
    float q = q2.x + q2.y;
    q += __shfl_xor(q, 1);
    q += __shfl_xor(q, 2);
    const int k = ((idx >> 1) << 4) + ci0 + (idx & 1);
    if (r == 0) zo[k << 4] = Cz - 0.5f * q;  // 16 lanes -> one 64B line
  }
#undef WT_OFF
#undef PB_OFF
}

// 4 threads per segment (b,h,w,ci); z cached in registers between max and sum.
__global__ __launch_bounds__(256) void seg_reduce(const float* __restrict__ z,
                                                  float* __restrict__ gmax,
                                                  float* __restrict__ gden) {
  const int tid = blockIdx.x * 256 + threadIdx.x;  // 0..131071
  const int part = tid & 3, ci = (tid >> 2) & 15, w2 = (tid >> 6) & 15;
  const int h = (tid >> 10) & 15, b = tid >> 14;
  float4 v[9];
  float m = -3.0e38f;
#pragma unroll
  for (int s = 0; s < 9; ++s) {
    const int ki = (s >= 6) ? 2 : (s >= 3) ? 1 : 0, kj = s - 3 * ki;
    const int pi = h - ki, pj = w2 - kj;
    if ((unsigned)pi < (unsigned)P_ && (unsigned)pj < (unsigned)P_) {
      v[s] = *(const float4*)(z + (size_t)(b * P2_ + pi * P_ + pj) * NV_ + s * 256 +
                              ci * 16 + part * 4);
    } else {
      v[s] = make_float4(-3.0e38f, -3.0e38f, -3.0e38f, -3.0e38f);
    }
    m = fmaxf(m, fmaxf(fmaxf(v[s].x, v[s].y), fmaxf(v[s].z, v[s].w)));
  }
  m = fmaxf(m, __shfl_xor(m, 1));
  m = fmaxf(m, __shfl_xor(m, 2));
  float s_ = 0.f;
#pragma unroll
  for (int s = 0; s < 9; ++s) {
    s_ += __expf(v[s].x - m) + __expf(v[s].y - m) + __expf(v[s].z - m) + __expf(v[s].w - m);
  }
  s_ += __shfl_xor(s_, 1);
  s_ += __shfl_xor(s_, 2);
  if (part == 0) {
    gmax[tid >> 2] = m;
    gden[tid >> 2] = s_;
  }
}
}  // namespace

extern "C" void kernel_launch(void* const* d_in, const int* in_sizes, int n_in,
                              void* d_out, int out_size, void* d_ws, size_t ws_size,
                              hipStream_t stream) {
  const float* pose = (const float*)d_in[0];
  const float* act = (const float*)d_in[1];
  const float* w = (const float*)d_in[2];
  const float* ba = (const float*)d_in[3];
  const float* bv = (const float*)d_in[4];
  float* out = (float*)d_out;

  float* z = (float*)d_ws;                  // 3,612,672 floats, layout [pid][k][o]
  float* gm = z + (size_t)B_ * P2_ * NV_;   // 32,768
  float* gd = gm + B_ * H_ * H_ * CI_;      // 32,768
  float* wt = gd + B_ * H_ * H_ * CI_;      // 36,864
  float* pt = wt + 36864;                   // 524,288 (pose transposed)

  const int NB = B_ * P2_;  // 1568 blocks, one per patch
  transpose_all<<<2192, 256, 0, stream>>>(pose, pt, w, wt);
  caps_main<0><<<NB, 512, 0, stream>>>(pt, act, wt, ba, bv, z, gm, gd, z, out);
  seg_reduce<<<512, 256, 0, stream>>>(z, gm, gd);
  caps_main<1><<<NB, 512, 0, stream>>>(pt, act, wt, ba, bv, z, gm, gd, z, out);
  seg_reduce<<<512, 256, 0, stream>>>(z, gm, gd);
  caps_main<2><<<NB, 512, 0, stream>>>(pt, act, wt, ba, bv, z, gm, gd, z, out);
}